// Round 2
// baseline (337.480 us; speedup 1.0000x reference)
//
#include <hip/hip_runtime.h>

#define H_IMG 512
#define W_IMG 512
#define PLANES 96                  // 32 * 3
#define NPIX 25165824.0            // 96 * 512 * 512

#define TW 64
#define TH 16
#define HALO 5
#define IH (TH + 2 * HALO)         // 26 staged rows
#define SW 80                      // staged cols (float4-aligned window col0-8 .. col0+71)
#define NF4 (SW / 4)               // 20 float4 loads per row
#define VW (TW + 2 * HALO)         // 74 conv-input columns
#define SVSTR 76                   // sv stride (>=76 needed by float4 reads, %4==0)
#define TILES_X (W_IMG / TW)       // 8
#define TILES_Y (H_IMG / TH)       // 32

__global__ void ssim_zero(double* acc) {
    if (threadIdx.x == 0) acc[0] = 0.0;
}

__global__ void ssim_final(const double* __restrict__ acc, float* __restrict__ out) {
    if (threadIdx.x == 0) out[0] = (float)(1.0 - acc[0] / NPIX);
}

__global__ __launch_bounds__(256, 4)
void ssim_main(const float* __restrict__ img1,
               const float* __restrict__ img2,
               double* __restrict__ acc)
{
    // normalized 11-tap Gaussian, sigma=1.5 (matches reference _create_window)
    constexpr float G[11] = {
        0.00102838f, 0.00759875f, 0.03600077f, 0.10936070f, 0.21300540f,
        0.26601180f,
        0.21300540f, 0.10936070f, 0.03600077f, 0.00759875f, 0.00102838f };
    constexpr float C1 = 0.0001f;   // (0.01*1.0)^2
    constexpr float C2 = 0.0009f;   // (0.03*1.0)^2

    // LDS budget: 8320 + 8320 + 24320 = 40960 B exactly -> 4 blocks/CU
    __shared__ __align__(16) float s1[IH][SW];
    __shared__ __align__(16) float s2[IH][SW];
    __shared__ __align__(16) float sv[5][TH][SVSTR];

    const int tid   = threadIdx.x;
    const int tile  = blockIdx.x;    // 0..255
    const int plane = blockIdx.y;    // 0..95
    const int tx = tile % TILES_X;
    const int ty = tile / TILES_X;
    const int col0 = tx * TW;
    const int row0 = ty * TH;
    const float* __restrict__ p1 = img1 + (size_t)plane * (H_IMG * W_IMG);
    const float* __restrict__ p2 = img2 + (size_t)plane * (H_IMG * W_IMG);
    const bool xint = (tx > 0) && (tx < TILES_X - 1);   // block-uniform

    // ---- stage 0: global -> LDS, float4 loads/stores ----
    // staged col sc corresponds to global col  gc = col0 - 8 + sc
    for (int i = tid; i < IH * NF4; i += 256) {
        const int r = i / NF4;
        const int q = i - r * NF4;
        const int gr = row0 - HALO + r;
        const int gc = col0 - 8 + 4 * q;
        float4 a = make_float4(0.f, 0.f, 0.f, 0.f);
        float4 b = a;
        if ((unsigned)gr < (unsigned)H_IMG) {
            if (xint) {
                a = *(const float4*)(p1 + gr * W_IMG + gc);
                b = *(const float4*)(p2 + gr * W_IMG + gc);
            } else {
                float av[4], bv[4];
                #pragma unroll
                for (int j = 0; j < 4; ++j) {
                    const int g = gc + j;
                    const bool ok = (unsigned)g < (unsigned)W_IMG;
                    const int off = gr * W_IMG + (ok ? g : 0);
                    av[j] = ok ? p1[off] : 0.f;
                    bv[j] = ok ? p2[off] : 0.f;
                }
                a = make_float4(av[0], av[1], av[2], av[3]);
                b = make_float4(bv[0], bv[1], bv[2], bv[3]);
            }
        }
        *(float4*)&s1[r][4 * q] = a;
        *(float4*)&s2[r][4 * q] = b;
    }
    __syncthreads();

    // ---- stage 1: vertical 11-tap conv, 5 derived channels, 4 rows/task ----
    // conv-input column cidx (0..73) lives at staged col sc = cidx + 3
    for (int t = tid; t < (TH / 4) * VW; t += 256) {
        const int cidx = t % VW;
        const int r0 = (t / VW) * 4;
        const int sc = cidx + 3;
        float x1[14], x2[14], q11[14], q22[14], q12[14];
        #pragma unroll
        for (int j = 0; j < 14; ++j) {
            const float u = s1[r0 + j][sc];
            const float v = s2[r0 + j][sc];
            x1[j] = u;  x2[j] = v;
            q11[j] = u * u;  q22[j] = v * v;  q12[j] = u * v;
        }
        #pragma unroll
        for (int i = 0; i < 4; ++i) {
            float m1 = 0.f, m2 = 0.f, e11 = 0.f, e22 = 0.f, e12 = 0.f;
            #pragma unroll
            for (int k = 0; k < 11; ++k) {
                m1  = fmaf(G[k], x1[i + k],  m1);
                m2  = fmaf(G[k], x2[i + k],  m2);
                e11 = fmaf(G[k], q11[i + k], e11);
                e22 = fmaf(G[k], q22[i + k], e22);
                e12 = fmaf(G[k], q12[i + k], e12);
            }
            sv[0][r0 + i][cidx] = m1;
            sv[1][r0 + i][cidx] = m2;
            sv[2][r0 + i][cidx] = e11;
            sv[3][r0 + i][cidx] = e22;
            sv[4][r0 + i][cidx] = e12;
        }
    }
    __syncthreads();

    // ---- stage 2: horizontal 11-tap conv (float4 LDS reads) + SSIM ----
    // exactly one task per thread: 4 output pixels
    float lsum = 0.f;
    {
        const int c0 = (tid & 15) * 4;   // output cols c0..c0+3
        const int r  = tid >> 4;
        float res[5][4];
        #pragma unroll
        for (int ch = 0; ch < 5; ++ch) {
            float w[16];
            const float4* s = (const float4*)(&sv[ch][r][c0]);
            const float4 t0 = s[0], t1 = s[1], t2 = s[2], t3 = s[3];
            w[0]=t0.x;  w[1]=t0.y;  w[2]=t0.z;  w[3]=t0.w;
            w[4]=t1.x;  w[5]=t1.y;  w[6]=t1.z;  w[7]=t1.w;
            w[8]=t2.x;  w[9]=t2.y;  w[10]=t2.z; w[11]=t2.w;
            w[12]=t3.x; w[13]=t3.y; w[14]=t3.z; w[15]=t3.w;
            #pragma unroll
            for (int i = 0; i < 4; ++i) {
                float a5 = 0.f;
                #pragma unroll
                for (int k = 0; k < 11; ++k)
                    a5 = fmaf(G[k], w[i + k], a5);
                res[ch][i] = a5;
            }
        }
        #pragma unroll
        for (int i = 0; i < 4; ++i) {
            const float mu1 = res[0][i], mu2 = res[1][i];
            const float mu1s = mu1 * mu1, mu2s = mu2 * mu2, mu12 = mu1 * mu2;
            const float v11 = fmaxf(res[2][i] - mu1s, 0.f);
            const float v22 = fmaxf(res[3][i] - mu2s, 0.f);
            const float v12 = res[4][i] - mu12;
            const float num = (2.f * mu12 + C1) * (2.f * v12 + C2);
            const float den = (mu1s + mu2s + C1) * (v11 + v22 + C2);
            lsum = fmaf(num, __builtin_amdgcn_rcpf(den), lsum);
        }
    }

    // ---- block reduce (wave shuffle -> LDS aliased on dead s1) ----
    #pragma unroll
    for (int off = 32; off > 0; off >>= 1)
        lsum += __shfl_down(lsum, off, 64);
    float* wsum = &s1[0][0];   // s1 dead after stage 1 (barrier passed)
    const int wave = tid >> 6, lane = tid & 63;
    if (lane == 0) wsum[wave] = lsum;
    __syncthreads();
    if (tid == 0)
        atomicAdd(acc, (double)(wsum[0] + wsum[1] + wsum[2] + wsum[3]));
}

extern "C" void kernel_launch(void* const* d_in, const int* in_sizes, int n_in,
                              void* d_out, int out_size, void* d_ws, size_t ws_size,
                              hipStream_t stream) {
    const float* img1 = (const float*)d_in[0];
    const float* img2 = (const float*)d_in[1];
    float* out  = (float*)d_out;
    double* acc = (double*)d_ws;

    ssim_zero<<<dim3(1), dim3(64), 0, stream>>>(acc);
    ssim_main<<<dim3(TILES_X * TILES_Y, PLANES), dim3(256), 0, stream>>>(img1, img2, acc);
    ssim_final<<<dim3(1), dim3(64), 0, stream>>>(acc, out);
}

// Round 3
// 144.376 us; speedup vs baseline: 2.3375x; 2.3375x over previous
//
#include <hip/hip_runtime.h>

#define W_IMG 512
#define H_IMG 512
#define PLANES 96                  // 32 * 3
#define NPIX 25165824.0            // 96 * 512 * 512

#define TBW 128                    // output cols per block (1 col / thread)
#define SH  32                     // output rows per block
#define XT  (W_IMG / TBW)          // 4
#define YT  (H_IMG / SH)           // 16
#define NROWS (SH + 10)            // 42 streamed input rows per block
#define SCOLS 140                  // staged cols per row: [c0-6, c0+134)
#define NPAIR 70                   // float2 col-pairs per image row

__global__ void ssim_zero(double* acc) {
    if (threadIdx.x == 0) acc[0] = 0.0;
}

__global__ void ssim_final(const double* __restrict__ acc, float* __restrict__ out) {
    if (threadIdx.x == 0) out[0] = (float)(1.0 - acc[0] / NPIX);
}

__global__ __launch_bounds__(128, 3)
void ssim_main(const float* __restrict__ img1,
               const float* __restrict__ img2,
               double* __restrict__ acc)
{
    // normalized 11-tap Gaussian, sigma=1.5 (matches reference _create_window)
    constexpr float G[11] = {
        0.00102838f, 0.00759875f, 0.03600077f, 0.10936070f, 0.21300540f,
        0.26601180f,
        0.21300540f, 0.10936070f, 0.03600077f, 0.00759875f, 0.00102838f };
    constexpr float C1 = 0.0001f;
    constexpr float C2 = 0.0009f;

    // one input row staged, double-buffered; per col: {img1, img2} interleaved
    __shared__ __align__(16) float2 sbuf[2][SCOLS];
    __shared__ float wred[2];

    const int tid = threadIdx.x;
    const int tx = blockIdx.x & (XT - 1);
    const int ty = blockIdx.x >> 2;
    const int c0 = tx * TBW;
    const int r0 = ty * SH;
    const size_t pofs = (size_t)blockIdx.y * (H_IMG * W_IMG);
    const float* __restrict__ p1 = img1 + pofs;
    const float* __restrict__ p2 = img2 + pofs;

    // this thread's output column and aligned horizontal window
    const int c  = c0 + tid;          // 0..511, always valid
    const int w  = c - 5;             // window start (may be <0: staged zeros)
    const int we = w & ~1;            // even-aligned window start
    const int wl = we - (c0 - 6);     // local staged index of aligned window, even, 0..128
    const bool odd = (w & 1) != 0;

    // parity-shifted coefficient vector: H = sum_j Gp[j] * val[we + j]
    float Gp[12];
    Gp[0] = odd ? 0.f : G[0];
    #pragma unroll
    for (int j = 1; j <= 10; ++j) Gp[j] = odd ? G[j - 1] : G[j];
    Gp[11] = odd ? G[10] : 0.f;

    // staging assignment: thread t < 70 owns staged col pair (2t, 2t+1)
    const int gp = c0 - 6 + 2 * tid;  // global col of pair start (even)
    const bool sth = (tid < NPAIR);
    const bool cok = sth && (gp >= 0) && (gp < W_IMG);   // pairs never straddle edges

    float2 ra = make_float2(0.f, 0.f), rb = ra;

    auto LOADROW = [&](int s) {
        ra = make_float2(0.f, 0.f); rb = ra;
        const int gr = r0 - 5 + s;
        if (cok && (unsigned)gr < (unsigned)H_IMG) {
            const int off = gr * W_IMG + gp;
            ra = *(const float2*)(p1 + off);
            rb = *(const float2*)(p2 + off);
        }
    };

    float ring[5][11];   // 5 maps x 11 pending rows, statically indexed
    float lsum = 0.f;

    // ---- prologue: stage row 0, prefetch row 1 ----
    LOADROW(0);
    if (sth) *(float4*)&sbuf[0][2 * tid] = make_float4(ra.x, rb.x, ra.y, rb.y);
    LOADROW(1);
    __syncthreads();

    int cur = 0;
    for (int sb = 0; sb < 44; sb += 11) {
        #pragma unroll
        for (int j = 0; j < 11; ++j) {
            const int s = sb + j;    // streamed input row index; ring slot = s % 11 = j

            // stage row s+1 (loaded last iter) into the other buffer
            if (s + 1 < NROWS) {
                if (sth) *(float4*)&sbuf[cur ^ 1][2 * tid] =
                    make_float4(ra.x, rb.x, ra.y, rb.y);
            }
            // prefetch row s+2
            if (s + 2 < NROWS) LOADROW(s + 2);

            // ---- horizontal 11-tap on row s -> push 5 ring values ----
            if (s < NROWS) {
                const float4* pw = (const float4*)&sbuf[cur][wl];
                const float4 f0 = pw[0], f1 = pw[1], f2 = pw[2],
                             f3 = pw[3], f4 = pw[4], f5 = pw[5];
                const float av[12] = { f0.x,f0.z, f1.x,f1.z, f2.x,f2.z,
                                       f3.x,f3.z, f4.x,f4.z, f5.x,f5.z };
                const float bv[12] = { f0.y,f0.w, f1.y,f1.w, f2.y,f2.w,
                                       f3.y,f3.w, f4.y,f4.w, f5.y,f5.w };
                float m1 = 0.f, m2 = 0.f, h11 = 0.f, h22 = 0.f, h12 = 0.f;
                #pragma unroll
                for (int q = 0; q < 12; ++q) {
                    const float t1 = Gp[q] * av[q];
                    const float t2 = Gp[q] * bv[q];
                    m1 += t1;  m2 += t2;
                    h11 = fmaf(t1, av[q], h11);
                    h22 = fmaf(t2, bv[q], h22);
                    h12 = fmaf(t1, bv[q], h12);
                }
                ring[0][j] = m1;  ring[1][j] = m2;
                ring[2][j] = h11; ring[3][j] = h22; ring[4][j] = h12;
            }

            // ---- vertical 11-tap + SSIM for output row s-10 ----
            if (s >= 10 && s < NROWS) {
                float M1 = 0.f, M2 = 0.f, E11 = 0.f, E22 = 0.f, E12 = 0.f;
                #pragma unroll
                for (int k = 0; k < 11; ++k) {
                    const int sl = (j + 1 + k) % 11;   // compile-time
                    M1  = fmaf(G[k], ring[0][sl], M1);
                    M2  = fmaf(G[k], ring[1][sl], M2);
                    E11 = fmaf(G[k], ring[2][sl], E11);
                    E22 = fmaf(G[k], ring[3][sl], E22);
                    E12 = fmaf(G[k], ring[4][sl], E12);
                }
                const float mu1s = M1 * M1, mu2s = M2 * M2, mu12 = M1 * M2;
                const float v11 = fmaxf(E11 - mu1s, 0.f);
                const float v22 = fmaxf(E22 - mu2s, 0.f);
                const float v12 = E12 - mu12;
                const float num = fmaf(2.f, mu12, C1) * fmaf(2.f, v12, C2);
                const float den = (mu1s + mu2s + C1) * (v11 + v22 + C2);
                lsum = fmaf(num, __builtin_amdgcn_rcpf(den), lsum);
            }

            __syncthreads();
            cur ^= 1;
        }
    }

    // ---- block reduce + one atomic per block ----
    #pragma unroll
    for (int off = 32; off > 0; off >>= 1)
        lsum += __shfl_down(lsum, off, 64);
    const int wave = tid >> 6, lane = tid & 63;
    if (lane == 0) wred[wave] = lsum;
    __syncthreads();
    if (tid == 0)
        atomicAdd(acc, (double)(wred[0] + wred[1]));
}

extern "C" void kernel_launch(void* const* d_in, const int* in_sizes, int n_in,
                              void* d_out, int out_size, void* d_ws, size_t ws_size,
                              hipStream_t stream) {
    const float* img1 = (const float*)d_in[0];
    const float* img2 = (const float*)d_in[1];
    float* out  = (float*)d_out;
    double* acc = (double*)d_ws;

    ssim_zero<<<dim3(1), dim3(64), 0, stream>>>(acc);
    ssim_main<<<dim3(XT * YT, PLANES), dim3(128), 0, stream>>>(img1, img2, acc);
    ssim_final<<<dim3(1), dim3(64), 0, stream>>>(acc, out);
}